// Round 5
// baseline (886.705 us; speedup 1.0000x reference)
//
#include <hip/hip_runtime.h>
#include <math.h>

// Mamba forward, MI355X. Round 6:
//  - mfma_gemm_nt: 3-buffer depth-2 pipeline with COUNTED s_waitcnt vmcnt(4)
//    + raw s_barrier (T4): stage(s+2) issued during step s stays in flight
//    across the barrier; only stage(s+1) is required to have landed. BK=32,
//    48KB LDS -> 3 blocks/CU. Round-5 showed depth-1 dbuf with vmcnt(0) drain
//    is latency-bound (~5000 cyc/step vs ~1030 ideal, MfmaUtil 21%).
//  - dt_proj moved to MFMA (MODE=3: +bias, softplus epilogue) with K padded
//    48->128 (zero weight cols kill the B/C columns of xdbl); fp32 gemm_nt
//    deleted.
#define DM    768
#define DS    16
#define DI    1536
#define DTR   48
#define NB    2
#define NL    1024
#define NBL   (NB*NL)
#define NVOC  32000
#define XDL   128   // padded x_proj output leading dim (80 -> 128)

typedef __attribute__((ext_vector_type(8))) short bf16x8;   // 8 bf16 in 4 VGPRs
typedef __attribute__((ext_vector_type(4))) float floatx4;

static __device__ __forceinline__ float siluf(float x){ return x / (1.0f + expf(-x)); }
static __device__ __forceinline__ float softplusf(float x){ return (x > 20.0f) ? x : log1pf(expf(x)); }
static __device__ __forceinline__ unsigned short f2bf(float f){
    unsigned int u = __float_as_uint(f);
    u += 0x7FFFu + ((u >> 16) & 1u);          // RNE
    return (unsigned short)(u >> 16);
}

#define GLL16(g, l) __builtin_amdgcn_global_load_lds( \
    (const __attribute__((address_space(1))) unsigned int*)(g), \
    (__attribute__((address_space(3))) unsigned int*)(l), 16, 0, 0)

// ---------------- fp32 -> bf16 cast (n multiple of 4) ----------------
__global__ __launch_bounds__(256) void cast_bf16_kernel(const float* __restrict__ in,
        unsigned short* __restrict__ out, int n4){
    int i = blockIdx.x*256 + threadIdx.x;
    if (i >= n4) return;
    float4 v = ((const float4*)in)[i];
    ushort4 o = { f2bf(v.x), f2bf(v.y), f2bf(v.z), f2bf(v.w) };
    ((ushort4*)out)[i] = o;
}

// ---------------- x_proj cast with zero-pad 80 -> 128 rows, both layers ------
// out: [2][128][1536] bf16, in: [2][80][1536] f32
__global__ __launch_bounds__(256) void cast_pad_xproj_kernel(const float* __restrict__ in,
        unsigned short* __restrict__ out){
    int q = blockIdx.x*256 + threadIdx.x;           // quad index
    const int QL = 128*1536/4;                      // quads per layer
    if (q >= 2*QL) return;
    int layer = q / QL, rem = q - layer*QL;
    int row = rem / (1536/4), c4 = rem - row*(1536/4);
    ushort4 o = {0,0,0,0};
    if (row < 80){
        float4 v = ((const float4*)(in + ((size_t)layer*80 + row)*1536))[c4];
        o.x = f2bf(v.x); o.y = f2bf(v.y); o.z = f2bf(v.z); o.w = f2bf(v.w);
    }
    ((ushort4*)out)[q] = o;
}

// ---------------- dt_proj cast with zero-pad K 48 -> 128, both layers --------
// out: [2][1536][128] bf16, in: [2][1536][48] f32
__global__ __launch_bounds__(256) void cast_pad_dtw_kernel(const float* __restrict__ in,
        unsigned short* __restrict__ out){
    int q = blockIdx.x*256 + threadIdx.x;           // quad index (4 elems)
    if (q >= 2*1536*32) return;
    int row = q >> 5, qc = q & 31;                  // row over [2*1536]
    ushort4 o = {0,0,0,0};
    if (qc < 12){
        float4 v = *(const float4*)(in + (size_t)row*48 + qc*4);
        o.x = f2bf(v.x); o.y = f2bf(v.y); o.z = f2bf(v.z); o.w = f2bf(v.w);
    }
    ((ushort4*)out)[q] = o;
}

// ---------------- zero fill (n multiple of 4) ----------------
__global__ __launch_bounds__(256) void zero_f32_kernel(float* __restrict__ p, int n4){
    int i = blockIdx.x*256 + threadIdx.x;
    if (i >= n4) return;
    float4 z = {0.f,0.f,0.f,0.f};
    ((float4*)p)[i] = z;
}

// ---------------- embedding gather ----------------
__global__ __launch_bounds__(256) void embed_kernel(const int* __restrict__ ids,
        const float* __restrict__ emb, float* __restrict__ x){
    int i = blockIdx.x*256 + threadIdx.x;
    if (i >= NBL*DM) return;
    int row = i / DM, c = i - row*DM;
    x[i] = emb[(size_t)ids[row]*DM + c];
}

// ---------------- rmsnorm -> bf16 output (wave-shuffle reduce, 1 barrier) ----
__global__ __launch_bounds__(256) void rmsnorm_bf16_kernel(const float* __restrict__ x,
        const float* __restrict__ w, unsigned short* __restrict__ h){
    int row = blockIdx.x;
    const float* xr = x + (size_t)row*DM;
    __shared__ float red[4];
    int tid = threadIdx.x, lane = tid & 63, wv = tid >> 6;
    float s = 0.f;
    for (int c = tid; c < DM; c += 256){ float v = xr[c]; s += v*v; }
    #pragma unroll
    for (int o = 32; o > 0; o >>= 1) s += __shfl_xor(s, o, 64);
    if (lane == 0) red[wv] = s;
    __syncthreads();
    float tot = red[0] + red[1] + red[2] + red[3];
    float r = 1.0f / sqrtf(tot*(1.0f/DM) + 1e-5f);
    for (int c = tid; c < DM; c += 256) h[(size_t)row*DM + c] = f2bf(xr[c]*r*w[c]);
}

// ---------------- bf16 MFMA GEMM: C[M,N](f32) = A[M,K]bf16 * B[N,K]bf16^T ----
// Requires M%128==0, N%128==0, Kc%32==0. lda=ldb=K, ldc=N.
// 128x128 tile, BK=32, 3-buffer depth-2 global_load_lds pipeline with counted
// vmcnt: step s issues stage(s+2) (4 loads/thread), computes buf[s%3], then
// waits vmcnt(4) — stage(s+1) landed, stage(s+2) still in flight ACROSS the
// raw s_barrier (never drains to 0 mid-loop).
// XOR-swizzled LDS: 16B-chunk c of row holds source chunk c ^ f(row),
// f(row)=(row&3)^((row>>2)&3); inverse pre-applied to the per-lane GLOBAL
// source (LDS dest stays linear as global_load_lds requires); readers XOR
// the chunk index -> <=2-way bank aliasing (free).
// Block mapping: flat id -> bijective XCD-chunk swizzle (m204) -> M-fastest.
// MODE: 0 = store, 1 = read-add-store, 2 = atomicAdd (split-K over blockIdx.z),
//       3 = softplus(v + bias[gn]) store.
template<int MODE>
__global__ __launch_bounds__(256) void mfma_gemm_nt(const unsigned short* __restrict__ A,
        const unsigned short* __restrict__ B, float* __restrict__ C,
        const float* __restrict__ bias, int M, int N, int K, int Kc){
    __shared__ __align__(16) unsigned short Asm[3][128*32];
    __shared__ __align__(16) unsigned short Bsm[3][128*32];
    int tid = threadIdx.x;

    // ---- swizzled block mapping (x-y plane only; z = split-K chunk) ----
    int nwg  = gridDim.x * gridDim.y;
    int orig = blockIdx.y * gridDim.x + blockIdx.x;
    int q = nwg >> 3, r = nwg & 7;
    int xcd = orig & 7;
    int wg  = (xcd < r ? xcd*(q+1) : r*(q+1) + (xcd-r)*q) + (orig >> 3);
    int mb  = wg % gridDim.y;          // M fastest (gridDim.y = M/128)
    int nb  = wg / gridDim.y;
    int m0 = mb * 128, n0 = nb * 128;

    int lane = tid & 63;
    int quad = lane >> 4, l16 = lane & 15;
    int wave = tid >> 6;
    int wm = (wave >> 1) * 64, wn = (wave & 1) * 64;

    floatx4 acc[4][4] = {};

    // staging: round qr in {0,1} covers rows qr*64 + (tid>>2); dest chunk
    // c = tid&3; source chunk = c ^ f(row) = (tid&3)^((tid>>2)&3)^((tid>>4)&3)
    // (row bits 0..1 = (tid>>2)&3, row bits 2..3 include (tid>>4)&3; the +64
    // of round 1 doesn't change f). Per-thread constant.
    int srow = tid >> 2;                                              // 0..63
    int csrc = ((tid & 3) ^ ((tid >> 2) & 3) ^ ((tid >> 4) & 3)) * 8; // ushort off
    const unsigned short* Ag = A + (size_t)(m0 + srow) * K + csrc;
    const unsigned short* Bg = B + (size_t)(n0 + srow) * K + csrc;
    size_t half = (size_t)64 * K;

    int k0 = blockIdx.z * Kc;
    int nsteps = Kc >> 5;

#define STAGE(buf, step) do{ int kk_ = k0 + (step)*32;                      \
        GLL16(Ag + kk_,        &Asm[buf][(size_t)tid*8]);                   \
        GLL16(Ag + kk_ + half, &Asm[buf][2048 + (size_t)tid*8]);            \
        GLL16(Bg + kk_,        &Bsm[buf][(size_t)tid*8]);                   \
        GLL16(Bg + kk_ + half, &Bsm[buf][2048 + (size_t)tid*8]); }while(0)
#define WAITV4 asm volatile("s_waitcnt vmcnt(4)" ::: "memory")
#define WAITV0 asm volatile("s_waitcnt vmcnt(0)" ::: "memory")

    // prologue: fill depth 2
    STAGE(0, 0);
    if (nsteps > 1) STAGE(1, 1);
    if (nsteps > 1) { WAITV4; } else { WAITV0; }
    __builtin_amdgcn_s_barrier();
    __builtin_amdgcn_sched_barrier(0);

    int cur = 0;
    for (int s = 0; s < nsteps; s++){
        if (s + 2 < nsteps){
            int b2 = cur + 2; if (b2 >= 3) b2 -= 3;
            STAGE(b2, s + 2);
        }

        bf16x8 af[4], bff[4];
        #pragma unroll
        for (int i = 0; i < 4; i++){
            int ar = wm + i*16 + l16;
            af[i]  = *(const bf16x8*)&Asm[cur][ar*32 + ((quad ^ (ar & 3) ^ ((ar >> 2) & 3)))*8];
            int br = wn + i*16 + l16;
            bff[i] = *(const bf16x8*)&Bsm[cur][br*32 + ((quad ^ (br & 3) ^ ((br >> 2) & 3)))*8];
        }
        #pragma unroll
        for (int i = 0; i < 4; i++)
            #pragma unroll
            for (int j = 0; j < 4; j++)
                acc[i][j] = __builtin_amdgcn_mfma_f32_16x16x32_bf16(af[i], bff[j], acc[i][j], 0, 0, 0);

        if (s + 1 < nsteps){
            if (s + 2 < nsteps) { WAITV4; } else { WAITV0; }
            __builtin_amdgcn_s_barrier();
            __builtin_amdgcn_sched_barrier(0);
            cur = (cur + 1 == 3) ? 0 : cur + 1;
        }
    }
#undef STAGE
#undef WAITV4
#undef WAITV0

    // C/D layout: col = lane&15, row = quad*4 + reg   [m89-verified mapping]
    #pragma unroll
    for (int i = 0; i < 4; i++){
        int gm = m0 + wm + i*16 + quad*4;
        #pragma unroll
        for (int j = 0; j < 4; j++){
            int gn = n0 + wn + j*16 + l16;
            float* cp = C + (size_t)gm*N + gn;
            #pragma unroll
            for (int rr = 0; rr < 4; rr++){
                float v = acc[i][j][rr];
                if (MODE == 2){
                    atomicAdd(&cp[(size_t)rr*N], v);
                } else if (MODE == 3){
                    cp[(size_t)rr*N] = softplusf(v + bias[gn]);
                } else {
                    if (MODE == 1) v += cp[(size_t)rr*N];
                    cp[(size_t)rr*N] = v;
                }
            }
        }
    }
}

// ---------------- depthwise causal conv (k=4) + bias + silu, f32 + bf16 out --
__global__ __launch_bounds__(256) void conv_silu_kernel(const float* __restrict__ xz,
        const float* __restrict__ cw, const float* __restrict__ cb,
        float* __restrict__ xs, unsigned short* __restrict__ xs_bf){
    int i = blockIdx.x*256 + threadIdx.x;
    if (i >= NBL*DI) return;
    int bl = i / DI, d = i - bl*DI;
    int l = bl & (NL-1);
    float acc = cb[d];
    #pragma unroll
    for (int j = 0; j < 4; j++){
        int off = j - 3;
        if (l + off >= 0) acc += cw[d*4+j] * xz[(size_t)(bl + off)*(2*DI) + d];
    }
    float v = siluf(acc);
    xs[i] = v;
    xs_bf[i] = f2bf(v);
}

// ---------------- transpose: out[C,R] = in[R,C]^T (in has leading dim ldin) --
__global__ __launch_bounds__(256) void transpose_kernel(const float* __restrict__ in,
        float* __restrict__ out, int R, int Ccols, int ldin){
    __shared__ float tile[32][33];
    int c0 = blockIdx.x*32, r0 = blockIdx.y*32;
    int tx = threadIdx.x & 31, ty = threadIdx.x >> 5;
    #pragma unroll
    for (int i = 0; i < 32; i += 8){
        int r = r0 + ty + i, c = c0 + tx;
        tile[ty+i][tx] = (r < R && c < Ccols) ? in[(size_t)r*ldin + c] : 0.f;
    }
    __syncthreads();
    #pragma unroll
    for (int i = 0; i < 32; i += 8){
        int r = r0 + tx, c = c0 + ty + i;
        if (c < Ccols && r < R) out[(size_t)c*R + r] = tile[tx][ty+i];
    }
}

// ---------------- fused double transpose: NBL x DI -> DI x NBL, two arrays ---
__global__ __launch_bounds__(256) void transpose2_kernel(const float* __restrict__ in1,
        float* __restrict__ out1, const float* __restrict__ in2, float* __restrict__ out2){
    __shared__ float tile[32][33];
    int c0 = blockIdx.x*32, r0 = blockIdx.y*32;   // c over DI, r over NBL
    int tx = threadIdx.x & 31, ty = threadIdx.x >> 5;
    #pragma unroll
    for (int i = 0; i < 32; i += 8)
        tile[ty+i][tx] = in1[(size_t)(r0+ty+i)*DI + (c0+tx)];
    __syncthreads();
    #pragma unroll
    for (int i = 0; i < 32; i += 8)
        out1[(size_t)(c0+ty+i)*NBL + (r0+tx)] = tile[tx][ty+i];
    __syncthreads();
    #pragma unroll
    for (int i = 0; i < 32; i += 8)
        tile[ty+i][tx] = in2[(size_t)(r0+ty+i)*DI + (c0+tx)];
    __syncthreads();
    #pragma unroll
    for (int i = 0; i < 32; i += 8)
        out2[(size_t)(c0+ty+i)*NBL + (r0+tx)] = tile[tx][ty+i];
}

// ---------------- wave-inclusive prefix scan (64 lanes, no barriers) ---------
static __device__ __forceinline__ float wave_incl_scan(float v, int lane){
    #pragma unroll
    for (int s = 1; s < 64; s <<= 1){
        float t = __shfl_up(v, s, 64);
        if (lane >= s) v += t;
    }
    return v;
}

// ---------------- selective scan (reference numerics) ----------------
// One WAVE per (b,d) row: 16 elements/lane, pure shuffle scans, zero barriers.
// y_t may alias dt_t (per-wave row exclusivity; reads precede writes).
__global__ __launch_bounds__(256) void scan_kernel(const float* __restrict__ u_t,
        const float* dt_t, const float* __restrict__ xdbl_t,
        const float* __restrict__ A_log, const float* __restrict__ Dp,
        float* y_t){
    int tid = threadIdx.x, lane = tid & 63, w = tid >> 6;
    int bd = blockIdx.x*4 + w;
    int b = bd / DI, d = bd - b*DI;
    size_t rowoff = (size_t)d*NBL + b*NL;
    int l0 = lane*16;

    float d16[16], u16[16];
    #pragma unroll
    for (int q = 0; q < 4; q++){
        float4 v = ((const float4*)(dt_t + rowoff + l0))[q];
        d16[q*4+0]=v.x; d16[q*4+1]=v.y; d16[q*4+2]=v.z; d16[q*4+3]=v.w;
        float4 u = ((const float4*)(u_t + rowoff + l0))[q];
        u16[q*4+0]=u.x; u16[q*4+1]=u.y; u16[q*4+2]=u.z; u16[q*4+3]=u.w;
    }
    float pl[16], yac[16];
    float run = 0.f;
    #pragma unroll
    for (int r = 0; r < 16; r++){ run += d16[r]; pl[r] = run; yac[r] = 0.f; }
    float inc = wave_incl_scan(run, lane);
    float ex  = inc - run;
    float T   = __shfl(inc, 63, 64);
    #pragma unroll
    for (int r = 0; r < 16; r++) pl[r] += ex;

    for (int n = 0; n < DS; n++){
        float An = -expf(A_log[d*DS + n]);
        float Bv[16], Cv[16];
        #pragma unroll
        for (int q = 0; q < 4; q++){
            float4 bv = ((const float4*)(xdbl_t + (size_t)(DTR+n)*NBL + b*NL + l0))[q];
            Bv[q*4+0]=bv.x; Bv[q*4+1]=bv.y; Bv[q*4+2]=bv.z; Bv[q*4+3]=bv.w;
            float4 cv = ((const float4*)(xdbl_t + (size_t)(DTR+DS+n)*NBL + b*NL + l0))[q];
            Cv[q*4+0]=cv.x; Cv[q*4+1]=cv.y; Cv[q*4+2]=cv.z; Cv[q*4+3]=cv.w;
        }
        float e[16], zl[16];
        float zrun = 0.f;
        #pragma unroll
        for (int r = 0; r < 16; r++){
            e[r] = expf(An * (T - pl[r]));
            zrun += d16[r]*u16[r]*Bv[r]*e[r];
            zl[r] = zrun;
        }
        float zinc = wave_incl_scan(zrun, lane);
        float zex  = zinc - zrun;
        #pragma unroll
        for (int r = 0; r < 16; r++){
            float num = zex + zl[r];
            yac[r] += num / (e[r] + 1e-12f) * Cv[r];
        }
    }
    float Dv = Dp[d];
    #pragma unroll
    for (int q = 0; q < 4; q++){
        float4 yo;
        yo.x = yac[q*4+0] + u16[q*4+0]*Dv;
        yo.y = yac[q*4+1] + u16[q*4+1]*Dv;
        yo.z = yac[q*4+2] + u16[q*4+2]*Dv;
        yo.w = yac[q*4+3] + u16[q*4+3]*Dv;
        ((float4*)(y_t + rowoff + l0))[q] = yo;
    }
}

// ---------------- transpose y back + gate with silu(res), bf16 output --------
__global__ __launch_bounds__(256) void gate_transpose_kernel(const float* __restrict__ y_t,
        const float* __restrict__ xz, unsigned short* __restrict__ ys){
    __shared__ float tile[32][33];
    int c0 = blockIdx.x*32;   // bl tile
    int r0 = blockIdx.y*32;   // d tile
    int tx = threadIdx.x & 31, ty = threadIdx.x >> 5;
    #pragma unroll
    for (int i = 0; i < 32; i += 8)
        tile[ty+i][tx] = y_t[(size_t)(r0+ty+i)*NBL + (c0+tx)];
    __syncthreads();
    #pragma unroll
    for (int i = 0; i < 32; i += 8){
        int d  = r0 + tx;
        int bl = c0 + ty + i;
        float g = siluf(xz[(size_t)bl*(2*DI) + DI + d]);
        ys[(size_t)bl*DI + d] = f2bf(tile[tx][ty+i] * g);
    }
}

extern "C" void kernel_launch(void* const* d_in, const int* in_sizes, int n_in,
                              void* d_out, int out_size, void* d_ws, size_t ws_size,
                              hipStream_t stream){
    const int*   ids    = (const int*)d_in[0];
    const float* emb    = (const float*)d_in[1];
    const float* W_in   = (const float*)d_in[2];
    const float* convw  = (const float*)d_in[3];
    const float* convb  = (const float*)d_in[4];
    const float* xproj  = (const float*)d_in[5];
    const float* dtw    = (const float*)d_in[6];
    const float* dtbias = (const float*)d_in[7];
    const float* Alog   = (const float*)d_in[8];
    const float* Dpar   = (const float*)d_in[9];
    const float* Wout   = (const float*)d_in[10];
    const float* normw  = (const float*)d_in[11];
    const float* normf  = (const float*)d_in[12];
    float* out = (float*)d_out;

    // ---- workspace layout ----
    float* ws    = (float*)d_ws;
    float* x     = ws;                              // NBL*DM f32
    float* xz    = x     + (size_t)NBL*DM;          // NBL*2*DI f32
    float* xs    = xz    + (size_t)NBL*2*DI;        // NBL*DI f32
    float* xdbl  = xs    + (size_t)NBL*DI;          // NBL*XDL f32 (padded, 80 valid)
    float* xdblt = xdbl  + (size_t)NBL*XDL;         // 80*NBL f32
    float* dtb   = xdblt + (size_t)NBL*80;          // NBL*DI f32 (later: ys_bf as ushort)
    float* dtt   = dtb   + (size_t)NBL*DI;          // DI*NBL f32 (scan writes y here too)
    float* ut    = dtt   + (size_t)NBL*DI;          // DI*NBL f32
    unsigned short* h_bf   = (unsigned short*)(ut + (size_t)NBL*DI);   // NBL*DM
    unsigned short* emb_bf = h_bf    + (size_t)NBL*DM;                 // NVOC*DM
    unsigned short* win_bf = emb_bf  + (size_t)NVOC*DM;                // 2*2*DI*DM
    unsigned short* wout_bf= win_bf  + (size_t)2*2*DI*DM;              // 2*DM*DI
    unsigned short* xs_bf  = wout_bf + (size_t)2*DM*DI;                // NBL*DI
    unsigned short* xprojp = xs_bf   + (size_t)NBL*DI;                 // 2*128*1536 (zero-padded)
    unsigned short* xdbl_bf= xprojp  + (size_t)2*128*DI;               // NBL*XDL
    unsigned short* dtw_bf = xdbl_bf + (size_t)NBL*XDL;                // 2*1536*128 (zero-padded K)
    unsigned short* ys_bf  = (unsigned short*)dtb;
    float* yt = dtt;   // alias: scan writes y over dt (row-exclusive, safe)

    // ---- weight / emb casts (every call; ws is re-poisoned by harness) ----
    cast_bf16_kernel<<<(NVOC*DM/4 + 255)/256, 256, 0, stream>>>(emb, emb_bf, NVOC*DM/4);
    cast_bf16_kernel<<<(2*2*DI*DM/4 + 255)/256, 256, 0, stream>>>(W_in, win_bf, 2*2*DI*DM/4);
    cast_bf16_kernel<<<(2*DM*DI/4 + 255)/256, 256, 0, stream>>>(Wout, wout_bf, 2*DM*DI/4);
    cast_pad_xproj_kernel<<<(2*128*1536/4 + 255)/256, 256, 0, stream>>>(xproj, xprojp);
    cast_pad_dtw_kernel<<<(2*1536*32 + 255)/256, 256, 0, stream>>>(dtw, dtw_bf);

    embed_kernel<<<(NBL*DM + 255)/256, 256, 0, stream>>>(ids, emb, x);

    for (int i = 0; i < 2; i++){
        rmsnorm_bf16_kernel<<<NBL, 256, 0, stream>>>(x, normw + i*DM, h_bf);
        // xz = h @ W_in^T   (2048 x 3072, K=768) — bf16 MFMA
        mfma_gemm_nt<0><<<dim3(3072/128, NBL/128, 1), 256, 0, stream>>>(
                h_bf, win_bf + (size_t)i*2*DI*DM, xz, nullptr, NBL, 2*DI, DM, DM);
        conv_silu_kernel<<<(NBL*DI + 255)/256, 256, 0, stream>>>(xz, convw + i*DI*4, convb + i*DI, xs, xs_bf);
        // xdbl = xs @ x_proj^T   (2048 x 80->128pad, K=1536) — bf16 MFMA split-K
        zero_f32_kernel<<<(NBL*XDL/4 + 255)/256, 256, 0, stream>>>(xdbl, NBL*XDL/4);
        mfma_gemm_nt<2><<<dim3(1, NBL/128, 8), 256, 0, stream>>>(
                xs_bf, xprojp + (size_t)i*128*DI, xdbl, nullptr, NBL, XDL, DI, DI/8);
        // dt = softplus(xdbl[:, :48] @ dt_proj^T + bias): K padded 48->128
        // (weight cols 48..127 zero; xdbl cols 80..127 are zero) — bf16 MFMA
        cast_bf16_kernel<<<(NBL*XDL/4 + 255)/256, 256, 0, stream>>>(xdbl, xdbl_bf, NBL*XDL/4);
        mfma_gemm_nt<3><<<dim3(DI/128, NBL/128, 1), 256, 0, stream>>>(
                xdbl_bf, dtw_bf + (size_t)i*DI*XDL, dtb, dtbias + i*DI, NBL, DI, XDL, XDL);
        transpose_kernel<<<dim3(3,64),  256, 0, stream>>>(xdbl, xdblt, NBL, 80, XDL);
        transpose2_kernel<<<dim3(48,64), 256, 0, stream>>>(dtb, dtt, xs, ut);
        scan_kernel<<<NB*DI/4, 256, 0, stream>>>(ut, dtt, xdblt,
                Alog + (size_t)i*DI*DS, Dpar + i*DI, yt);
        gate_transpose_kernel<<<dim3(64,48), 256, 0, stream>>>(yt, xz, ys_bf);
        // x += ys @ W_out^T   (2048 x 768, K=1536) — bf16 MFMA split-K, atomic
        mfma_gemm_nt<2><<<dim3(DM/128, NBL/128, 2), 256, 0, stream>>>(
                ys_bf, wout_bf + (size_t)i*DM*DI, x, nullptr, NBL, DM, DI, DI/2);
    }

    rmsnorm_bf16_kernel<<<NBL, 256, 0, stream>>>(x, normf, h_bf);
    // logits = h @ emb^T   (2048 x 32000, K=768) — bf16 MFMA
    mfma_gemm_nt<0><<<dim3(NVOC/128, NBL/128, 1), 256, 0, stream>>>(
            h_bf, emb_bf, out, nullptr, NBL, NVOC, DM, DM);
}

// Round 6
// 843.096 us; speedup vs baseline: 1.0517x; 1.0517x over previous
//
#include <hip/hip_runtime.h>
#include <math.h>

// Mamba forward, MI355X. Round 7:
//  - gemm256: 256x256-tile 8-phase pipelined bf16 MFMA GEMM (m201 template,
//    plain HIP) for the logits GEMM. 8 waves (2Mx4N, interleaved M so each
//    half-tile frees after 2 phases), BK=64, 128KB LDS (2dbuf x 2half x
//    128x64 x {A,B}), XOR-8 swizzle (proven R4/R5 pair), counted vmcnt
//    (8/10, never 0 mid-loop), setprio around MFMA clusters, 2 barriers/phase.
//    Round-6 showed the 128^2 4-wave tile is LDS-read-BW-capped (~770cyc
//    ds_read vs 516 MFMA per K-step) and sync-bound at MfmaUtil 24%.
//  - dt_proj reverted to fp32 gemm_nt (R6's MFMA swap regressed non-logits).
#define DM    768
#define DS    16
#define DI    1536
#define DTR   48
#define NB    2
#define NL    1024
#define NBL   (NB*NL)
#define NVOC  32000
#define XDL   128   // padded x_proj output leading dim (80 -> 128)

typedef __attribute__((ext_vector_type(8))) short bf16x8;   // 8 bf16 in 4 VGPRs
typedef __attribute__((ext_vector_type(4))) float floatx4;

static __device__ __forceinline__ float siluf(float x){ return x / (1.0f + expf(-x)); }
static __device__ __forceinline__ float softplusf(float x){ return (x > 20.0f) ? x : log1pf(expf(x)); }
static __device__ __forceinline__ unsigned short f2bf(float f){
    unsigned int u = __float_as_uint(f);
    u += 0x7FFFu + ((u >> 16) & 1u);          // RNE
    return (unsigned short)(u >> 16);
}

#define GLL16(g, l) __builtin_amdgcn_global_load_lds( \
    (const __attribute__((address_space(1))) unsigned int*)(g), \
    (__attribute__((address_space(3))) unsigned int*)(l), 16, 0, 0)

#define WAITVM(n) do{ asm volatile("s_waitcnt vmcnt(" #n ")" ::: "memory"); \
                      __builtin_amdgcn_sched_barrier(0); }while(0)

// ---------------- fp32 -> bf16 cast (n multiple of 4) ----------------
__global__ __launch_bounds__(256) void cast_bf16_kernel(const float* __restrict__ in,
        unsigned short* __restrict__ out, int n4){
    int i = blockIdx.x*256 + threadIdx.x;
    if (i >= n4) return;
    float4 v = ((const float4*)in)[i];
    ushort4 o = { f2bf(v.x), f2bf(v.y), f2bf(v.z), f2bf(v.w) };
    ((ushort4*)out)[i] = o;
}

// ---------------- x_proj cast with zero-pad 80 -> 128 rows, both layers ------
__global__ __launch_bounds__(256) void cast_pad_xproj_kernel(const float* __restrict__ in,
        unsigned short* __restrict__ out){
    int q = blockIdx.x*256 + threadIdx.x;           // quad index
    const int QL = 128*1536/4;                      // quads per layer
    if (q >= 2*QL) return;
    int layer = q / QL, rem = q - layer*QL;
    int row = rem / (1536/4), c4 = rem - row*(1536/4);
    ushort4 o = {0,0,0,0};
    if (row < 80){
        float4 v = ((const float4*)(in + ((size_t)layer*80 + row)*1536))[c4];
        o.x = f2bf(v.x); o.y = f2bf(v.y); o.z = f2bf(v.z); o.w = f2bf(v.w);
    }
    ((ushort4*)out)[q] = o;
}

// ---------------- zero fill (n multiple of 4) ----------------
__global__ __launch_bounds__(256) void zero_f32_kernel(float* __restrict__ p, int n4){
    int i = blockIdx.x*256 + threadIdx.x;
    if (i >= n4) return;
    float4 z = {0.f,0.f,0.f,0.f};
    ((float4*)p)[i] = z;
}

// ---------------- embedding gather ----------------
__global__ __launch_bounds__(256) void embed_kernel(const int* __restrict__ ids,
        const float* __restrict__ emb, float* __restrict__ x){
    int i = blockIdx.x*256 + threadIdx.x;
    if (i >= NBL*DM) return;
    int row = i / DM, c = i - row*DM;
    x[i] = emb[(size_t)ids[row]*DM + c];
}

// ---------------- rmsnorm -> bf16 output (wave-shuffle reduce, 1 barrier) ----
__global__ __launch_bounds__(256) void rmsnorm_bf16_kernel(const float* __restrict__ x,
        const float* __restrict__ w, unsigned short* __restrict__ h){
    int row = blockIdx.x;
    const float* xr = x + (size_t)row*DM;
    __shared__ float red[4];
    int tid = threadIdx.x, lane = tid & 63, wv = tid >> 6;
    float s = 0.f;
    for (int c = tid; c < DM; c += 256){ float v = xr[c]; s += v*v; }
    #pragma unroll
    for (int o = 32; o > 0; o >>= 1) s += __shfl_xor(s, o, 64);
    if (lane == 0) red[wv] = s;
    __syncthreads();
    float tot = red[0] + red[1] + red[2] + red[3];
    float r = 1.0f / sqrtf(tot*(1.0f/DM) + 1e-5f);
    for (int c = tid; c < DM; c += 256) h[(size_t)row*DM + c] = f2bf(xr[c]*r*w[c]);
}

// ================= gemm256: 256x256 8-phase bf16 MFMA GEMM ==================
// C[M,N](f32) = A[M,K]bf16 * B[N,K]bf16^T.  M%256==0, N%256==0, K%64==0, K>=128.
// 512 threads = 8 waves (wr=wave>>2 in 0..1, wc=wave&3 in 0..3).
// Wave output 128x64, M-interleaved: m-frag j (0..7) covers rows j*32+wr*16.
// A halves: rows 0..127 (frags j0-3) / 128..255 (j4-7): each half's LDS is
// only read during 2 of the 4 phases -> stage legality windows for prefetch.
// LDS halves [128][64] bf16, rows 128B; chunk c of row r holds global chunk
// c ^ (r&7) (inverse pre-applied to per-lane GLOBAL src; linear dest as
// global_load_lds requires; reads XOR back) -> 2-way max aliasing (free,
// proven 0-conflict in R4/R5).
// Per tile t (4 phases): P1 {ds A-h0(8)+B-lo(4); stage A1[t+1]; bar; MFMA
// j0-3 x fn0-1; bar}  P2 {ds B-hi(4); stage A0[t+2]; bar; MFMA j0-3 x fn2-3;
// vmcnt(10); bar}  P3 {ds A-h1(8); stage B0[t+2]; bar; MFMA j4-7 x fn0-1;
// bar}  P4 {stage B1[t+2]; bar; MFMA j4-7 x fn2-3; vmcnt(8); bar}.
// Waits counted per-wave THEN barrier -> all waves' halves landed (m218/T4:
// never drain vmcnt to 0 in the main loop; B halves get 5-6 phases of
// HBM-latency cover). Tail tiles tighten counts per issue-guard arithmetic.
__global__ __launch_bounds__(512, 2) void gemm256(const unsigned short* __restrict__ A,
        const unsigned short* __restrict__ B, float* __restrict__ C,
        int M, int N, int K){
    __shared__ __align__(16) unsigned short Asm[2][2][128*64];
    __shared__ __align__(16) unsigned short Bsm[2][2][128*64];
    int tid = threadIdx.x;

    int nwg  = gridDim.x * gridDim.y;
    int orig = blockIdx.y * gridDim.x + blockIdx.x;
    int qq = nwg >> 3, r8 = nwg & 7;
    int xcd = orig & 7;
    int wg  = (xcd < r8 ? xcd*(qq+1) : r8*(qq+1) + (xcd-r8)*qq) + (orig >> 3);
    int mb  = wg % gridDim.y;            // M fastest (gridDim.y = M/256)
    int nb  = wg / gridDim.y;
    int m0 = mb*256, n0 = nb*256;

    int lane = tid & 63, wave = tid >> 6;
    int wr = wave >> 2, wc = wave & 3;
    int quad = lane >> 4, l16 = lane & 15;

    int srow = tid >> 3;                                   // 0..63
    int csrc = ((tid & 7) ^ ((tid >> 3) & 7)) * 8;         // pre-swizzled src
    const unsigned short* Ag = A + (size_t)(m0 + srow)*K + csrc;
    const unsigned short* Bg = B + (size_t)(n0 + srow)*K + csrc;
    int NT = K >> 6;

    floatx4 acc[8][4] = {};

#define ST_A(tt, h) do{ \
    GLL16(Ag + (size_t)((h)*128)*K      + (size_t)(tt)*64, &Asm[(tt)&1][h][(size_t)tid*8]); \
    GLL16(Ag + (size_t)((h)*128 + 64)*K + (size_t)(tt)*64, &Asm[(tt)&1][h][4096 + (size_t)tid*8]); \
}while(0)
#define ST_B(tt, h) do{ \
    GLL16(Bg + (size_t)((h)*128)*K      + (size_t)(tt)*64, &Bsm[(tt)&1][h][(size_t)tid*8]); \
    GLL16(Bg + (size_t)((h)*128 + 64)*K + (size_t)(tt)*64, &Bsm[(tt)&1][h][4096 + (size_t)tid*8]); \
}while(0)
#define LDA_(tt, h, jj, ks) (*(const bf16x8*)&Asm[(tt)&1][h][((jj)*32 + wr*16 + l16)*64 + ((((ks)*4 + quad) ^ (l16 & 7))*8)])
#define LDB_(tt, k, ks)     (*(const bf16x8*)&Bsm[(tt)&1][wc>>1][((wc&1)*64 + (k)*16 + l16)*64 + ((((ks)*4 + quad) ^ (l16 & 7))*8)])
#define MM(d, x, y) d = __builtin_amdgcn_mfma_f32_16x16x32_bf16(x, y, d, 0, 0, 0)

    // prologue: A0[0], B0[0], B1[0], A1[0], A0[1], B0[1], B1[1]
    ST_A(0, 0); ST_B(0, 0); ST_B(0, 1); ST_A(0, 1);
    if (NT > 1){ ST_A(1, 0); ST_B(1, 0); ST_B(1, 1); WAITVM(8); }
    else       { WAITVM(0); }
    __builtin_amdgcn_s_barrier();

    for (int t = 0; t < NT; ++t){
        bf16x8 a[8], b0[4], b1[4];
        // ---- P1: ds A-h0 + B-lo; stage A1[t+1]; MFMA j0-3 x fn0-1 ----
        #pragma unroll
        for (int jj = 0; jj < 4; jj++){
            a[jj*2+0] = LDA_(t, 0, jj, 0);
            a[jj*2+1] = LDA_(t, 0, jj, 1);
        }
        #pragma unroll
        for (int k = 0; k < 2; k++){
            b0[k*2+0] = LDB_(t, k, 0);
            b0[k*2+1] = LDB_(t, k, 1);
        }
        if (t + 1 < NT) ST_A(t+1, 1);
        __builtin_amdgcn_s_barrier();
        __builtin_amdgcn_s_setprio(1);
        #pragma unroll
        for (int jj = 0; jj < 4; jj++)
            #pragma unroll
            for (int fn = 0; fn < 2; fn++){
                MM(acc[jj][fn], a[jj*2+0], b0[fn*2+0]);
                MM(acc[jj][fn], a[jj*2+1], b0[fn*2+1]);
            }
        __builtin_amdgcn_s_setprio(0);
        __builtin_amdgcn_s_barrier();

        // ---- P2: ds B-hi; stage A0[t+2]; MFMA j0-3 x fn2-3; vmcnt ----
        #pragma unroll
        for (int k = 0; k < 2; k++){
            b1[k*2+0] = LDB_(t, k+2, 0);
            b1[k*2+1] = LDB_(t, k+2, 1);
        }
        if (t + 2 < NT) ST_A(t+2, 0);
        __builtin_amdgcn_s_barrier();
        __builtin_amdgcn_s_setprio(1);
        #pragma unroll
        for (int jj = 0; jj < 4; jj++)
            #pragma unroll
            for (int fn = 0; fn < 2; fn++){
                MM(acc[jj][fn+2], a[jj*2+0], b1[fn*2+0]);
                MM(acc[jj][fn+2], a[jj*2+1], b1[fn*2+1]);
            }
        __builtin_amdgcn_s_setprio(0);
        if (t == NT-1)      { WAITVM(0); }   // pin A1[t] for P3's ds_read
        else if (t == NT-2) { WAITVM(8); }
        else                { WAITVM(10); }
        __builtin_amdgcn_s_barrier();

        // ---- P3: ds A-h1; stage B0[t+2]; MFMA j4-7 x fn0-1 ----
        #pragma unroll
        for (int jj = 0; jj < 4; jj++){
            a[jj*2+0] = LDA_(t, 1, jj, 0);
            a[jj*2+1] = LDA_(t, 1, jj, 1);
        }
        if (t + 2 < NT) ST_B(t+2, 0);
        __builtin_amdgcn_s_barrier();
        __builtin_amdgcn_s_setprio(1);
        #pragma unroll
        for (int jj = 0; jj < 4; jj++)
            #pragma unroll
            for (int fn = 0; fn < 2; fn++){
                MM(acc[4+jj][fn], a[jj*2+0], b0[fn*2+0]);
                MM(acc[4+jj][fn], a[jj*2+1], b0[fn*2+1]);
            }
        __builtin_amdgcn_s_setprio(0);
        __builtin_amdgcn_s_barrier();

        // ---- P4: stage B1[t+2]; MFMA j4-7 x fn2-3; vmcnt for tile t+1 ----
        if (t + 2 < NT) ST_B(t+2, 1);
        __builtin_amdgcn_s_barrier();
        __builtin_amdgcn_s_setprio(1);
        #pragma unroll
        for (int jj = 0; jj < 4; jj++)
            #pragma unroll
            for (int fn = 0; fn < 2; fn++){
                MM(acc[4+jj][fn+2], a[jj*2+0], b1[fn*2+0]);
                MM(acc[4+jj][fn+2], a[jj*2+1], b1[fn*2+1]);
            }
        __builtin_amdgcn_s_setprio(0);
        if (t + 1 < NT){
            if (t == NT-2) { WAITVM(2); }
            else           { WAITVM(8); }
        }
        __builtin_amdgcn_s_barrier();
    }
#undef ST_A
#undef ST_B
#undef LDA_
#undef LDB_
#undef MM

    // C/D: col = lane&15, row = quad*4 + reg   [m89-verified mapping]
    #pragma unroll
    for (int j = 0; j < 8; j++){
        int gm = m0 + j*32 + wr*16 + quad*4;
        #pragma unroll
        for (int fn = 0; fn < 4; fn++){
            int gn = n0 + wc*64 + fn*16 + l16;
            float* cp = C + (size_t)gm*N + gn;
            #pragma unroll
            for (int rr = 0; rr < 4; rr++)
                cp[(size_t)rr*N] = acc[j][fn][rr];
        }
    }
}

// ---------------- bf16 MFMA GEMM (128^2): C = A * B^T ----
// 3-buffer depth-2 counted-vmcnt pipeline, BK=32 (see R6 notes).
// MODE: 0 = store, 1 = read-add-store, 2 = atomicAdd (split-K over blockIdx.z).
template<int MODE>
__global__ __launch_bounds__(256) void mfma_gemm_nt(const unsigned short* __restrict__ A,
        const unsigned short* __restrict__ B, float* __restrict__ C,
        const float* __restrict__ bias, int M, int N, int K, int Kc){
    __shared__ __align__(16) unsigned short Asm[3][128*32];
    __shared__ __align__(16) unsigned short Bsm[3][128*32];
    int tid = threadIdx.x;

    int nwg  = gridDim.x * gridDim.y;
    int orig = blockIdx.y * gridDim.x + blockIdx.x;
    int q = nwg >> 3, r = nwg & 7;
    int xcd = orig & 7;
    int wg  = (xcd < r ? xcd*(q+1) : r*(q+1) + (xcd-r)*q) + (orig >> 3);
    int mb  = wg % gridDim.y;          // M fastest (gridDim.y = M/128)
    int nb  = wg / gridDim.y;
    int m0 = mb * 128, n0 = nb * 128;

    int lane = tid & 63;
    int quad = lane >> 4, l16 = lane & 15;
    int wave = tid >> 6;
    int wm = (wave >> 1) * 64, wn = (wave & 1) * 64;

    floatx4 acc[4][4] = {};

    int srow = tid >> 2;                                              // 0..63
    int csrc = ((tid & 3) ^ ((tid >> 2) & 3) ^ ((tid >> 4) & 3)) * 8; // ushort off
    const unsigned short* Ag = A + (size_t)(m0 + srow) * K + csrc;
    const unsigned short* Bg = B + (size_t)(n0 + srow) * K + csrc;
    size_t half = (size_t)64 * K;

    int k0 = blockIdx.z * Kc;
    int nsteps = Kc >> 5;

#define STAGE(buf, step) do{ int kk_ = k0 + (step)*32;                      \
        GLL16(Ag + kk_,        &Asm[buf][(size_t)tid*8]);                   \
        GLL16(Ag + kk_ + half, &Asm[buf][2048 + (size_t)tid*8]);            \
        GLL16(Bg + kk_,        &Bsm[buf][(size_t)tid*8]);                   \
        GLL16(Bg + kk_ + half, &Bsm[buf][2048 + (size_t)tid*8]); }while(0)

    // prologue: fill depth 2
    STAGE(0, 0);
    if (nsteps > 1) STAGE(1, 1);
    if (nsteps > 1) { WAITVM(4); } else { WAITVM(0); }
    __builtin_amdgcn_s_barrier();

    int cur = 0;
    for (int s = 0; s < nsteps; s++){
        if (s + 2 < nsteps){
            int b2 = cur + 2; if (b2 >= 3) b2 -= 3;
            STAGE(b2, s + 2);
        }

        bf16x8 af[4], bff[4];
        #pragma unroll
        for (int i = 0; i < 4; i++){
            int ar = wm + i*16 + l16;
            af[i]  = *(const bf16x8*)&Asm[cur][ar*32 + ((quad ^ (ar & 3) ^ ((ar >> 2) & 3)))*8];
            int br = wn + i*16 + l16;
            bff[i] = *(const bf16x8*)&Bsm[cur][br*32 + ((quad ^ (br & 3) ^ ((br >> 2) & 3)))*8];
        }
        #pragma unroll
        for (int i = 0; i < 4; i++)
            #pragma unroll
            for (int j = 0; j < 4; j++)
                acc[i][j] = __builtin_amdgcn_mfma_f32_16x16x32_bf16(af[i], bff[j], acc[i][j], 0, 0, 0);

        if (s + 1 < nsteps){
            if (s + 2 < nsteps) { WAITVM(4); } else { WAITVM(0); }
            __builtin_amdgcn_s_barrier();
            cur = (cur + 1 == 3) ? 0 : cur + 1;
        }
    }
#undef STAGE

    // C/D layout: col = lane&15, row = quad*4 + reg   [m89-verified mapping]
    #pragma unroll
    for (int i = 0; i < 4; i++){
        int gm = m0 + wm + i*16 + quad*4;
        #pragma unroll
        for (int j = 0; j < 4; j++){
            int gn = n0 + wn + j*16 + l16;
            float* cp = C + (size_t)gm*N + gn;
            #pragma unroll
            for (int rr = 0; rr < 4; rr++){
                float v = acc[i][j][rr];
                if (MODE == 2){
                    atomicAdd(&cp[(size_t)rr*N], v);
                } else {
                    if (MODE == 1) v += cp[(size_t)rr*N];
                    cp[(size_t)rr*N] = v;
                }
            }
        }
    }
}

// ---------------- fp32 tiled GEMM (small shapes): C = A * Bw^T ----------------
__global__ __launch_bounds__(256) void gemm_nt(const float* __restrict__ A,
        const float* __restrict__ Bw, float* __restrict__ C, const float* __restrict__ bias,
        int M, int N, int K, int lda, int ldb, int ldc, int act, int accum){
    __shared__ float As[16][68];
    __shared__ float Bs[16][68];
    int tid = threadIdx.x;
    int tn = tid & 15, tm = tid >> 4;
    int n0 = blockIdx.x * 64, m0 = blockIdx.y * 64;
    float acc[4][4] = {{0.f}};
    for (int kt = 0; kt < K; kt += 16){
        int gk = kt + tn;
        bool kok = gk < K;
        #pragma unroll
        for (int r = 0; r < 4; r++){
            int m = tm + r*16;
            As[tn][m] = (kok && (m0 + m) < M) ? A[(size_t)(m0+m)*lda + gk] : 0.f;
            Bs[tn][m] = (kok && (n0 + m) < N) ? Bw[(size_t)(n0+m)*ldb + gk] : 0.f;
        }
        __syncthreads();
        #pragma unroll
        for (int kk = 0; kk < 16; kk++){
            float a0 = As[kk][tm*4+0], a1 = As[kk][tm*4+1], a2 = As[kk][tm*4+2], a3 = As[kk][tm*4+3];
            float b0 = Bs[kk][tn*4+0], b1 = Bs[kk][tn*4+1], b2 = Bs[kk][tn*4+2], b3 = Bs[kk][tn*4+3];
            acc[0][0] += a0*b0; acc[0][1] += a0*b1; acc[0][2] += a0*b2; acc[0][3] += a0*b3;
            acc[1][0] += a1*b0; acc[1][1] += a1*b1; acc[1][2] += a1*b2; acc[1][3] += a1*b3;
            acc[2][0] += a2*b0; acc[2][1] += a2*b1; acc[2][2] += a2*b2; acc[2][3] += a2*b3;
            acc[3][0] += a3*b0; acc[3][1] += a3*b1; acc[3][2] += a3*b2; acc[3][3] += a3*b3;
        }
        __syncthreads();
    }
    #pragma unroll
    for (int i = 0; i < 4; i++){
        int gm = m0 + tm*4 + i;
        if (gm >= M) continue;
        #pragma unroll
        for (int j = 0; j < 4; j++){
            int gn = n0 + tn*4 + j;
            if (gn >= N) continue;
            float v = acc[i][j];
            if (bias) v += bias[gn];
            if (act == 1) v = softplusf(v);
            size_t ci = (size_t)gm*ldc + gn;
            if (accum) v += C[ci];
            C[ci] = v;
        }
    }
}

// ---------------- depthwise causal conv (k=4) + bias + silu, f32 + bf16 out --
__global__ __launch_bounds__(256) void conv_silu_kernel(const float* __restrict__ xz,
        const float* __restrict__ cw, const float* __restrict__ cb,
        float* __restrict__ xs, unsigned short* __restrict__ xs_bf){
    int i = blockIdx.x*256 + threadIdx.x;
    if (i >= NBL*DI) return;
    int bl = i / DI, d = i - bl*DI;
    int l = bl & (NL-1);
    float acc = cb[d];
    #pragma unroll
    for (int j = 0; j < 4; j++){
        int off = j - 3;
        if (l + off >= 0) acc += cw[d*4+j] * xz[(size_t)(bl + off)*(2*DI) + d];
    }
    float v = siluf(acc);
    xs[i] = v;
    xs_bf[i] = f2bf(v);
}

// ---------------- transpose: out[C,R] = in[R,C]^T (in has leading dim ldin) --
__global__ __launch_bounds__(256) void transpose_kernel(const float* __restrict__ in,
        float* __restrict__ out, int R, int Ccols, int ldin){
    __shared__ float tile[32][33];
    int c0 = blockIdx.x*32, r0 = blockIdx.y*32;
    int tx = threadIdx.x & 31, ty = threadIdx.x >> 5;
    #pragma unroll
    for (int i = 0; i < 32; i += 8){
        int r = r0 + ty + i, c = c0 + tx;
        tile[ty+i][tx] = (r < R && c < Ccols) ? in[(size_t)r*ldin + c] : 0.f;
    }
    __syncthreads();
    #pragma unroll
    for (int i = 0; i < 32; i += 8){
        int r = r0 + tx, c = c0 + ty + i;
        if (c < Ccols && r < R) out[(size_t)c*R + r] = tile[tx][ty+i];
    }
}

// ---------------- fused double transpose: NBL x DI -> DI x NBL, two arrays ---
__global__ __launch_bounds__(256) void transpose2_kernel(const float* __restrict__ in1,
        float* __restrict__ out1, const float* __restrict__ in2, float* __restrict__ out2){
    __shared__ float tile[32][33];
    int c0 = blockIdx.x*32, r0 = blockIdx.y*32;   // c over DI, r over NBL
    int tx = threadIdx.x & 31, ty = threadIdx.x >> 5;
    #pragma unroll
    for (int i = 0; i < 32; i += 8)
        tile[ty+i][tx] = in1[(size_t)(r0+ty+i)*DI + (c0+tx)];
    __syncthreads();
    #pragma unroll
    for (int i = 0; i < 32; i += 8)
        out1[(size_t)(c0+ty+i)*NBL + (r0+tx)] = tile[tx][ty+i];
    __syncthreads();
    #pragma unroll
    for (int i = 0; i < 32; i += 8)
        tile[ty+i][tx] = in2[(size_t)(r0+ty+i)*DI + (c0+tx)];
    __syncthreads();
    #pragma unroll
    for (int i = 0; i < 32; i += 8)
        out2[(size_t)(c0+ty+i)*NBL + (r0+tx)] = tile[tx][ty+i];
}

// ---------------- wave-inclusive prefix scan (64 lanes, no barriers) ---------
static __device__ __forceinline__ float wave_incl_scan(float v, int lane){
    #pragma unroll
    for (int s = 1; s < 64; s <<= 1){
        float t = __shfl_up(v, s, 64);
        if (lane >= s) v += t;
    }
    return v;
}

// ---------------- selective scan (reference numerics) ----------------
__global__ __launch_bounds__(256) void scan_kernel(const float* __restrict__ u_t,
        const float* dt_t, const float* __restrict__ xdbl_t,
        const float* __restrict__ A_log, const float* __restrict__ Dp,
        float* y_t){
    int tid = threadIdx.x, lane = tid & 63, w = tid >> 6;
    int bd = blockIdx.x*4 + w;
    int b = bd / DI, d = bd - b*DI;
    size_t rowoff = (size_t)d*NBL + b*NL;
    int l0 = lane*16;

    float d16[16], u16[16];
    #pragma unroll
    for (int q = 0; q < 4; q++){
        float4 v = ((const float4*)(dt_t + rowoff + l0))[q];
        d16[q*4+0]=v.x; d16[q*4+1]=v.y; d16[q*4+2]=v.z; d16[q*4+3]=v.w;
        float4 u = ((const float4*)(u_t + rowoff + l0))[q];
        u16[q*4+0]=u.x; u16[q*4+1]=u.y; u16[q*4+2]=u.z; u16[q*4+3]=u.w;
    }
    float pl[16], yac[16];
    float run = 0.f;
    #pragma unroll
    for (int r = 0; r < 16; r++){ run += d16[r]; pl[r] = run; yac[r] = 0.f; }
    float inc = wave_incl_scan(run, lane);
    float ex  = inc - run;
    float T   = __shfl(inc, 63, 64);
    #pragma unroll
    for (int r = 0; r < 16; r++) pl[r] += ex;

    for (int n = 0; n < DS; n++){
        float An = -expf(A_log[d*DS + n]);
        float Bv[16], Cv[16];
        #pragma unroll
        for (int q = 0; q < 4; q++){
            float4 bv = ((const float4*)(xdbl_t + (size_t)(DTR+n)*NBL + b*NL + l0))[q];
            Bv[q*4+0]=bv.x; Bv[q*4+1]=bv.y; Bv[q*4+2]=bv.z; Bv[q*4+3]=bv.w;
            float4 cv = ((const float4*)(xdbl_t + (size_t)(DTR+DS+n)*NBL + b*NL + l0))[q];
            Cv[q*4+0]=cv.x; Cv[q*4+1]=cv.y; Cv[q*4+2]=cv.z; Cv[q*4+3]=cv.w;
        }
        float e[16], zl[16];
        float zrun = 0.f;
        #pragma unroll
        for (int r = 0; r < 16; r++){
            e[r] = expf(An * (T - pl[r]));
            zrun += d16[r]*u16[r]*Bv[r]*e[r];
            zl[r] = zrun;
        }
        float zinc = wave_incl_scan(zrun, lane);
        float zex  = zinc - zrun;
        #pragma unroll
        for (int r = 0; r < 16; r++){
            float num = zex + zl[r];
            yac[r] += num / (e[r] + 1e-12f) * Cv[r];
        }
    }
    float Dv = Dp[d];
    #pragma unroll
    for (int q = 0; q < 4; q++){
        float4 yo;
        yo.x = yac[q*4+0] + u16[q*4+0]*Dv;
        yo.y = yac[q*4+1] + u16[q*4+1]*Dv;
        yo.z = yac[q*4+2] + u16[q*4+2]*Dv;
        yo.w = yac[q*4+3] + u16[q*4+3]*Dv;
        ((float4*)(y_t + rowoff + l0))[q] = yo;
    }
}

// ---------------- transpose y back + gate with silu(res), bf16 output --------
__global__ __launch_bounds__(256) void gate_transpose_kernel(const float* __restrict__ y_t,
        const float* __restrict__ xz, unsigned short* __restrict__ ys){
    __shared__ float tile[32][33];
    int c0 = blockIdx.x*32;   // bl tile
    int r0 = blockIdx.y*32;   // d tile
    int tx = threadIdx.x & 31, ty = threadIdx.x >> 5;
    #pragma unroll
    for (int i = 0; i < 32; i += 8)
        tile[ty+i][tx] = y_t[(size_t)(r0+ty+i)*NBL + (c0+tx)];
    __syncthreads();
    #pragma unroll
    for (int i = 0; i < 32; i += 8){
        int d  = r0 + tx;
        int bl = c0 + ty + i;
        float g = siluf(xz[(size_t)bl*(2*DI) + DI + d]);
        ys[(size_t)bl*DI + d] = f2bf(tile[tx][ty+i] * g);
    }
}

extern "C" void kernel_launch(void* const* d_in, const int* in_sizes, int n_in,
                              void* d_out, int out_size, void* d_ws, size_t ws_size,
                              hipStream_t stream){
    const int*   ids    = (const int*)d_in[0];
    const float* emb    = (const float*)d_in[1];
    const float* W_in   = (const float*)d_in[2];
    const float* convw  = (const float*)d_in[3];
    const float* convb  = (const float*)d_in[4];
    const float* xproj  = (const float*)d_in[5];
    const float* dtw    = (const float*)d_in[6];
    const float* dtbias = (const float*)d_in[7];
    const float* Alog   = (const float*)d_in[8];
    const float* Dpar   = (const float*)d_in[9];
    const float* Wout   = (const float*)d_in[10];
    const float* normw  = (const float*)d_in[11];
    const float* normf  = (const float*)d_in[12];
    float* out = (float*)d_out;

    // ---- workspace layout ----
    float* ws    = (float*)d_ws;
    float* x     = ws;                              // NBL*DM f32
    float* xz    = x     + (size_t)NBL*DM;          // NBL*2*DI f32
    float* xs    = xz    + (size_t)NBL*2*DI;        // NBL*DI f32
    float* xdbl  = xs    + (size_t)NBL*DI;          // NBL*XDL f32 (padded, 80 valid)
    float* xdblt = xdbl  + (size_t)NBL*XDL;         // 80*NBL f32
    float* dtb   = xdblt + (size_t)NBL*80;          // NBL*DI f32 (later: ys_bf as ushort)
    float* dtt   = dtb   + (size_t)NBL*DI;          // DI*NBL f32 (scan writes y here too)
    float* ut    = dtt   + (size_t)NBL*DI;          // DI*NBL f32
    unsigned short* h_bf   = (unsigned short*)(ut + (size_t)NBL*DI);   // NBL*DM
    unsigned short* emb_bf = h_bf    + (size_t)NBL*DM;                 // NVOC*DM
    unsigned short* win_bf = emb_bf  + (size_t)NVOC*DM;                // 2*2*DI*DM
    unsigned short* wout_bf= win_bf  + (size_t)2*2*DI*DM;              // 2*DM*DI
    unsigned short* xs_bf  = wout_bf + (size_t)2*DM*DI;                // NBL*DI
    unsigned short* xprojp = xs_bf   + (size_t)NBL*DI;                 // 2*128*1536 (zero-padded)
    unsigned short* ys_bf  = (unsigned short*)dtb;
    float* yt = dtt;   // alias: scan writes y over dt (row-exclusive, safe)

    // ---- weight / emb casts (every call; ws is re-poisoned by harness) ----
    cast_bf16_kernel<<<(NVOC*DM/4 + 255)/256, 256, 0, stream>>>(emb, emb_bf, NVOC*DM/4);
    cast_bf16_kernel<<<(2*2*DI*DM/4 + 255)/256, 256, 0, stream>>>(W_in, win_bf, 2*2*DI*DM/4);
    cast_bf16_kernel<<<(2*DM*DI/4 + 255)/256, 256, 0, stream>>>(Wout, wout_bf, 2*DM*DI/4);
    cast_pad_xproj_kernel<<<(2*128*1536/4 + 255)/256, 256, 0, stream>>>(xproj, xprojp);

    embed_kernel<<<(NBL*DM + 255)/256, 256, 0, stream>>>(ids, emb, x);

    for (int i = 0; i < 2; i++){
        rmsnorm_bf16_kernel<<<NBL, 256, 0, stream>>>(x, normw + i*DM, h_bf);
        // xz = h @ W_in^T   (2048 x 3072, K=768) — bf16 MFMA
        mfma_gemm_nt<0><<<dim3(3072/128, NBL/128, 1), 256, 0, stream>>>(
                h_bf, win_bf + (size_t)i*2*DI*DM, xz, nullptr, NBL, 2*DI, DM, DM);
        conv_silu_kernel<<<(NBL*DI + 255)/256, 256, 0, stream>>>(xz, convw + i*DI*4, convb + i*DI, xs, xs_bf);
        // xdbl = xs @ x_proj^T   (2048 x 80->128pad, K=1536) — bf16 MFMA split-K
        zero_f32_kernel<<<(NBL*XDL/4 + 255)/256, 256, 0, stream>>>(xdbl, NBL*XDL/4);
        mfma_gemm_nt<2><<<dim3(1, NBL/128, 8), 256, 0, stream>>>(
                xs_bf, xprojp + (size_t)i*128*DI, xdbl, nullptr, NBL, XDL, DI, DI/8);
        // dt = softplus(xdbl[:, :48] @ dt_proj^T + bias)   (2048 x 1536, K=48) — fp32
        gemm_nt<<<dim3(24,32), 256, 0, stream>>>(xdbl, dtw + (size_t)i*DI*DTR, dtb, dtbias + i*DI,
                NBL, DI, DTR, XDL, DTR, DI, 1, 0);
        transpose_kernel<<<dim3(3,64),  256, 0, stream>>>(xdbl, xdblt, NBL, 80, XDL);
        transpose2_kernel<<<dim3(48,64), 256, 0, stream>>>(dtb, dtt, xs, ut);
        scan_kernel<<<NB*DI/4, 256, 0, stream>>>(ut, dtt, xdblt,
                Alog + (size_t)i*DI*DS, Dpar + i*DI, yt);
        gate_transpose_kernel<<<dim3(64,48), 256, 0, stream>>>(yt, xz, ys_bf);
        // x += ys @ W_out^T   (2048 x 768, K=1536) — bf16 MFMA split-K, atomic
        mfma_gemm_nt<2><<<dim3(DM/128, NBL/128, 2), 256, 0, stream>>>(
                ys_bf, wout_bf + (size_t)i*DM*DI, x, nullptr, NBL, DM, DI, DI/2);
    }

    rmsnorm_bf16_kernel<<<NBL, 256, 0, stream>>>(x, normf, h_bf);
    // logits = h @ emb^T   (2048 x 32000, K=768) — 256^2 8-phase bf16 MFMA
    gemm256<<<dim3(NVOC/256, NBL/256), 512, 0, stream>>>(
            h_bf, emb_bf, out, NBL, NVOC, DM);
}